// Round 7
// baseline (756.248 us; speedup 1.0000x reference)
//
#include <hip/hip_runtime.h>

#define N_NODES 50000
#define N_EDGES 800000
#define D 128
#define NUM_GRAPHS 128

typedef __attribute__((ext_vector_type(8)))  short bfrag8;
typedef __attribute__((ext_vector_type(16))) float f32x16;

__device__ __forceinline__ float4 f4zero() { return make_float4(0.f, 0.f, 0.f, 0.f); }

__device__ __forceinline__ unsigned short f2bf(float f) {
    unsigned u = __float_as_uint(f);
    unsigned r = (u + 0x7fffu + ((u >> 16) & 1u)) >> 16;
    return (unsigned short)r;
}
__device__ __forceinline__ float bf2f(unsigned short b) {
    return __uint_as_float(((unsigned)b) << 16);
}
__device__ __forceinline__ float4 bf2f4(ushort4 u) {
    return make_float4(bf2f(u.x), bf2f(u.y), bf2f(u.z), bf2f(u.w));
}
__device__ __forceinline__ float4 bnrelu(float4 v, float4 a, float4 b) {
    v.x = fmaxf(a.x * v.x + b.x, 0.f);
    v.y = fmaxf(a.y * v.y + b.y, 0.f);
    v.z = fmaxf(a.z * v.z + b.z, 0.f);
    v.w = fmaxf(a.w * v.w + b.w, 0.f);
    return v;
}
__device__ __forceinline__ void acc4(float4& a, float4 u) {
    a.x += u.x; a.y += u.y; a.z += u.z; a.w += u.w;
}

// ===========================================================================
// prep: W->Wt (bf16, transposed), x->bf16, zero deg, zero stats
// grid = 512 (wconv) + 6250 (xconv) + 196 (deg) + 1 (stats) = 6959
// ===========================================================================
__global__ __launch_bounds__(256) void prep_kernel(
    const float* __restrict__ W1, const float* __restrict__ W2,
    const float* __restrict__ x, short* __restrict__ Wt,
    ushort4* __restrict__ Hb, int* __restrict__ deg, float* __restrict__ stats)
{
    int b = blockIdx.x, t = threadIdx.x;
    if (b < 512) {
        int idx = b * 256 + t;                 // 131072 = 8*128*128
        int m = idx >> 14, rem = idx & 16383;
        int k = rem >> 7, n = rem & 127;
        const float* W = (m < 4) ? (W1 + (size_t)m * 16384)
                                 : (W2 + (size_t)(m - 4) * 16384);
        Wt[(size_t)m * 16384 + n * 128 + k] = (short)f2bf(W[k * 128 + n]);
    } else if (b < 6762) {
        int i = (b - 512) * 256 + t;           // N*32 = 1,600,000 exactly
        float4 v = ((const float4*)x)[i];
        Hb[i] = make_ushort4(f2bf(v.x), f2bf(v.y), f2bf(v.z), f2bf(v.w));
    } else if (b < 6958) {
        int i = (b - 6762) * 256 + t;
        if (i < N_NODES) deg[i] = 0;
    } else {
        stats[t] = 0.f;                        // statsSum[128] ++ statsSq[128]
    }
}

// ===========================================================================
// CSR build: hist (+ per-edge insertion pos), block scan, fixup, fill
// ===========================================================================
__global__ __launch_bounds__(256) void hist_kernel(
    const int* __restrict__ dst, int* __restrict__ deg,
    int* __restrict__ edge_pos)
{
    int e = blockIdx.x * 256 + threadIdx.x;
    if (e < N_EDGES) edge_pos[e] = atomicAdd(&deg[dst[e]], 1);
}

__global__ __launch_bounds__(256) void scan_block_kernel(
    const int* __restrict__ deg, int* __restrict__ row_ptr,
    int* __restrict__ blockSum)
{
    __shared__ int wsum[4];
    int t = threadIdx.x, b = blockIdx.x;
    int i = b * 256 + t;
    int v = (i < N_NODES) ? deg[i] : 0;
    int lane = t & 63, wid = t >> 6;
    #pragma unroll
    for (int off = 1; off < 64; off <<= 1) {
        int u = __shfl_up(v, off, 64);
        if (lane >= off) v += u;
    }
    if (lane == 63) wsum[wid] = v;
    __syncthreads();
    int add = 0;
    for (int w = 0; w < wid; ++w) add += wsum[w];
    v += add;
    if (i < N_NODES) row_ptr[i + 1] = v;
    if (t == 255) blockSum[b] = v;
}

// every block locally scans the 196 partials, adds its exclusive offset
__global__ __launch_bounds__(256) void scan_fixup_kernel(
    const int* __restrict__ blockSum, int* __restrict__ row_ptr, int nb)
{
    __shared__ int wsum[4];
    __shared__ int sbuf[256];
    int t = threadIdx.x, b = blockIdx.x;
    int v = (t < nb) ? blockSum[t] : 0;
    int lane = t & 63, wid = t >> 6;
    #pragma unroll
    for (int off = 1; off < 64; off <<= 1) {
        int u = __shfl_up(v, off, 64);
        if (lane >= off) v += u;
    }
    if (lane == 63) wsum[wid] = v;
    __syncthreads();
    int add = 0;
    for (int w = 0; w < wid; ++w) add += wsum[w];
    sbuf[t] = v + add;
    __syncthreads();
    if (b == 0 && t == 0) row_ptr[0] = 0;
    if (b > 0) {
        int off = sbuf[b - 1];
        int i = b * 256 + t;
        if (i < N_NODES) row_ptr[i + 1] += off;
    }
}

__global__ __launch_bounds__(256) void fill_kernel(
    const int* __restrict__ src, const int* __restrict__ dst,
    const int* __restrict__ row_ptr, const int* __restrict__ edge_pos,
    int* __restrict__ csr_src)
{
    int e = blockIdx.x * 256 + threadIdx.x;
    if (e >= N_EDGES) return;
    csr_src[row_ptr[dst[e]] + edge_pos[e]] = src[e];
}

// ===========================================================================
// Fused layer:  Hout = (relu(A@W1+b1))@W2 + b2,  A gathered on the fly:
//   A[n] = (1+eps)*y(h[n]) + sum_{j in N(n)} y(h[j]),  y = prev BN+ReLU
// Block = 128 thr = 2 waves = 64 nodes. LDS: A-tile 16KB (XOR-swizzled,
// reused for z1 and z2) + W 32KB (W1 then W2). 3 blocks/CU.
// A/B frags via swizzled ds_read_b128; C/D 32x32: col=ct*32+(lane&31),
// row=(r&3)+8*(r>>2)+4*(lane>>5). H ping-pongs (gather reads arbitrary rows).
// ===========================================================================
__global__ __launch_bounds__(128, 2) void layer_kernel(
    const ushort4* __restrict__ H, const int* __restrict__ row_ptr,
    const int* __restrict__ csr_src,
    const short* __restrict__ Wt1, const short* __restrict__ Wt2,
    const float* __restrict__ bias1, const float* __restrict__ bias2,
    const float* __restrict__ abn, const float* __restrict__ bbn,
    const float* __restrict__ epsp,
    ushort* __restrict__ Hout,
    float* __restrict__ statsSum, float* __restrict__ statsSq, int M)
{
    __shared__ __align__(16) short Alds[64 * 128];    // 16 KB
    __shared__ __align__(16) short Wlds[128 * 128];   // 32 KB
    __shared__ float ssum[128];
    __shared__ float ssq[128];

    const int tid   = threadIdx.x;
    const int wv    = tid >> 6;
    const int lane  = tid & 63;
    const int half  = lane >> 5;
    const int ln    = lane & 31;
    const int row0  = blockIdx.x * 64;
    const int wrow0 = wv * 32;
    const bool doStats = (statsSum != nullptr);
    if (doStats) { ssum[tid] = 0.f; ssq[tid] = 0.f; }

    // ---- stage W1 -> Wlds (chunk c of row n at c^(n&15)) ----
    {
        const int4* Wg = (const int4*)Wt1;
        int4* Wl = (int4*)Wlds;
        #pragma unroll
        for (int i = 0; i < 16; ++i) {
            int id = i * 128 + tid;
            int n = id >> 4, c = id & 15;
            Wl[n * 16 + (c ^ (n & 15))] = Wg[id];
        }
    }

    // ---- gather phase: group g (32 lanes) -> block rows g*16..g*16+15 ----
    {
        const int g  = tid >> 5;
        const int c4 = tid & 31;
        const bool bn = (abn != nullptr);
        float4 sa = make_float4(1.f, 1.f, 1.f, 1.f);
        float4 sb = f4zero();
        if (bn) { sa = ((const float4*)abn)[c4]; sb = ((const float4*)bbn)[c4]; }
        const float eps1 = 1.0f + *epsp;
        for (int i = 0; i < 16; ++i) {
            int brow = g * 16 + i;
            int node = row0 + brow;
            float4 acc = f4zero();
            if (node < M) {
                float4 v = bf2f4(H[node * 32 + c4]);
                if (bn) v = bnrelu(v, sa, sb);
                acc = make_float4(eps1 * v.x, eps1 * v.y, eps1 * v.z, eps1 * v.w);
                int beg = row_ptr[node], end = row_ptr[node + 1];
                for (int base = beg; base < end; base += 32) {
                    int idx = (base + c4 < end) ? csr_src[base + c4] : 0;
                    int cnt = min(32, end - base);
                    int j = 0;
                    for (; j + 8 <= cnt; j += 8) {
                        int s0 = __shfl(idx, j + 0, 32), s1 = __shfl(idx, j + 1, 32);
                        int s2 = __shfl(idx, j + 2, 32), s3 = __shfl(idx, j + 3, 32);
                        int s4 = __shfl(idx, j + 4, 32), s5 = __shfl(idx, j + 5, 32);
                        int s6 = __shfl(idx, j + 6, 32), s7 = __shfl(idx, j + 7, 32);
                        float4 u0 = bf2f4(H[s0 * 32 + c4]);
                        float4 u1 = bf2f4(H[s1 * 32 + c4]);
                        float4 u2 = bf2f4(H[s2 * 32 + c4]);
                        float4 u3 = bf2f4(H[s3 * 32 + c4]);
                        float4 u4 = bf2f4(H[s4 * 32 + c4]);
                        float4 u5 = bf2f4(H[s5 * 32 + c4]);
                        float4 u6 = bf2f4(H[s6 * 32 + c4]);
                        float4 u7 = bf2f4(H[s7 * 32 + c4]);
                        if (bn) {
                            u0 = bnrelu(u0, sa, sb); u1 = bnrelu(u1, sa, sb);
                            u2 = bnrelu(u2, sa, sb); u3 = bnrelu(u3, sa, sb);
                            u4 = bnrelu(u4, sa, sb); u5 = bnrelu(u5, sa, sb);
                            u6 = bnrelu(u6, sa, sb); u7 = bnrelu(u7, sa, sb);
                        }
                        acc4(acc, u0); acc4(acc, u1); acc4(acc, u2); acc4(acc, u3);
                        acc4(acc, u4); acc4(acc, u5); acc4(acc, u6); acc4(acc, u7);
                    }
                    for (; j < cnt; ++j) {
                        int s = __shfl(idx, j, 32);
                        float4 u = bf2f4(H[s * 32 + c4]);
                        if (bn) u = bnrelu(u, sa, sb);
                        acc4(acc, u);
                    }
                }
            }
            int cch = c4 >> 1, hh = c4 & 1;
            *(ushort4*)(Alds + brow * 128 + ((cch ^ (brow & 15)) << 3) + hh * 4) =
                make_ushort4(f2bf(acc.x), f2bf(acc.y), f2bf(acc.z), f2bf(acc.w));
        }
    }
    __syncthreads();   // Wlds(W1) staged by both waves; Alds own-wave only

    // ---- GEMM1: z1 = relu(A@W1 + b1) -> Alds (swizzled, bf16) ----
    {
        f32x16 acc[4];
        #pragma unroll
        for (int ct = 0; ct < 4; ++ct)
            #pragma unroll
            for (int r = 0; r < 16; ++r) acc[ct][r] = 0.f;

        bfrag8 af[8];
        int arow = wrow0 + ln;
        #pragma unroll
        for (int kk = 0; kk < 8; ++kk) {
            int c = kk * 2 + half;
            af[kk] = *(const bfrag8*)(Alds + arow * 128 + ((c ^ (arow & 15)) << 3));
        }
        #pragma unroll
        for (int kk = 0; kk < 8; ++kk) {
            int c = kk * 2 + half;
            #pragma unroll
            for (int ct = 0; ct < 4; ++ct) {
                int n = ct * 32 + ln;
                bfrag8 bf = *(const bfrag8*)(Wlds + n * 128 + ((c ^ (n & 15)) << 3));
                acc[ct] = __builtin_amdgcn_mfma_f32_32x32x16_bf16(
                    af[kk], bf, acc[ct], 0, 0, 0);
            }
        }
        #pragma unroll
        for (int ct = 0; ct < 4; ++ct) {
            int col = ct * 32 + ln;
            int cc = col >> 3, co = col & 7;
            float bv = bias1[col];
            #pragma unroll
            for (int r = 0; r < 16; ++r) {
                int brow = wrow0 + (r & 3) + 8 * (r >> 2) + 4 * half;
                float v = fmaxf(acc[ct][r] + bv, 0.f);
                Alds[brow * 128 + ((cc ^ (brow & 15)) << 3) + co] = (short)f2bf(v);
            }
        }
    }
    __syncthreads();   // both waves done reading Wlds(W1)

    // ---- stage W2 -> Wlds ----
    {
        const int4* Wg = (const int4*)Wt2;
        int4* Wl = (int4*)Wlds;
        #pragma unroll
        for (int i = 0; i < 16; ++i) {
            int id = i * 128 + tid;
            int n = id >> 4, c = id & 15;
            Wl[n * 16 + (c ^ (n & 15))] = Wg[id];
        }
    }
    __syncthreads();

    // ---- GEMM2: z2 = z1 @ W2 + b2 -> Alds; stats on fp32 values ----
    {
        f32x16 acc[4];
        #pragma unroll
        for (int ct = 0; ct < 4; ++ct)
            #pragma unroll
            for (int r = 0; r < 16; ++r) acc[ct][r] = 0.f;

        bfrag8 af[8];
        int arow = wrow0 + ln;
        #pragma unroll
        for (int kk = 0; kk < 8; ++kk) {
            int c = kk * 2 + half;
            af[kk] = *(const bfrag8*)(Alds + arow * 128 + ((c ^ (arow & 15)) << 3));
        }
        #pragma unroll
        for (int kk = 0; kk < 8; ++kk) {
            int c = kk * 2 + half;
            #pragma unroll
            for (int ct = 0; ct < 4; ++ct) {
                int n = ct * 32 + ln;
                bfrag8 bf = *(const bfrag8*)(Wlds + n * 128 + ((c ^ (n & 15)) << 3));
                acc[ct] = __builtin_amdgcn_mfma_f32_32x32x16_bf16(
                    af[kk], bf, acc[ct], 0, 0, 0);
            }
        }
        #pragma unroll
        for (int ct = 0; ct < 4; ++ct) {
            int col = ct * 32 + ln;
            int cc = col >> 3, co = col & 7;
            float bv = bias2[col];
            float s = 0.f, sq = 0.f;
            #pragma unroll
            for (int r = 0; r < 16; ++r) {
                int brow = wrow0 + (r & 3) + 8 * (r >> 2) + 4 * half;
                float v = acc[ct][r] + bv;
                Alds[brow * 128 + ((cc ^ (brow & 15)) << 3) + co] = (short)f2bf(v);
                if (row0 + brow < M) { s += v; sq += v * v; }
            }
            if (doStats) {
                s  += __shfl_xor(s, 32);
                sq += __shfl_xor(sq, 32);
                if (half == 0) {
                    atomicAdd(&ssum[col], s);
                    atomicAdd(&ssq[col], sq);
                }
            }
        }
    }

    // ---- coalesced store: own-wave rows of Alds -> Hout ----
    {
        const int4* zl = (const int4*)Alds;
        int4* Ho = (int4*)Hout;
        #pragma unroll
        for (int i = 0; i < 8; ++i) {
            int id = i * 64 + lane;            // 512 = 32 rows x 16 chunks
            int brow = wrow0 + (id >> 4);
            int c = id & 15;
            int grow = row0 + brow;
            if (grow < M)
                Ho[(size_t)grow * 16 + c] = zl[brow * 16 + (c ^ (brow & 15))];
        }
    }
    if (doStats) {
        __syncthreads();
        atomicAdd(&statsSum[tid], ssum[tid]);
        atomicAdd(&statsSq[tid],  ssq[tid]);
    }
}

// ===========================================================================
// BN stats -> per-column scale/bias; re-zero stats for next layer
// ===========================================================================
__global__ void bnscale_kernel(
    float* __restrict__ sum, float* __restrict__ sq,
    const float* __restrict__ gamma, const float* __restrict__ beta,
    float* __restrict__ a, float* __restrict__ b)
{
    int c = threadIdx.x;
    float invN = 1.0f / (float)N_NODES;
    float mu = sum[c] * invN;
    float var = sq[c] * invN - mu * mu;
    float ai = gamma[c] * rsqrtf(var + 1e-5f);
    a[c] = ai;
    b[c] = beta[c] - mu * ai;
    sum[c] = 0.f;
    sq[c] = 0.f;
}

// ===========================================================================
// global_add_pool (bf16 in): batch sorted -> run-length accumulate.
// ===========================================================================
__global__ __launch_bounds__(256) void pool_kernel(
    const ushort4* __restrict__ H, const int* __restrict__ batch,
    float* __restrict__ out)
{
    int c4 = threadIdx.x & 31;
    int nl = threadIdx.x >> 5;
    int node0 = blockIdx.x * 256;
    float4 acc = f4zero();
    int gcur = -1;
    for (int i = nl; i < 256; i += 8) {
        int n = node0 + i;
        if (n >= N_NODES) break;
        int g = batch[n];
        if (g != gcur) {
            if (gcur >= 0) {
                float* o = out + gcur * D + c4 * 4;
                atomicAdd(o + 0, acc.x); atomicAdd(o + 1, acc.y);
                atomicAdd(o + 2, acc.z); atomicAdd(o + 3, acc.w);
            }
            gcur = g;
            acc = f4zero();
        }
        float4 v = bf2f4(H[n * 32 + c4]);
        acc4(acc, v);
    }
    if (gcur >= 0) {
        float* o = out + gcur * D + c4 * 4;
        atomicAdd(o + 0, acc.x); atomicAdd(o + 1, acc.y);
        atomicAdd(o + 2, acc.z); atomicAdd(o + 3, acc.w);
    }
}

extern "C" void kernel_launch(void* const* d_in, const int* in_sizes, int n_in,
                              void* d_out, int out_size, void* d_ws, size_t ws_size,
                              hipStream_t stream)
{
    const float* x     = (const float*)d_in[0];
    const int*   ei    = (const int*)d_in[1];
    const int*   batch = (const int*)d_in[2];
    const float* W1    = (const float*)d_in[3];
    const float* b1    = (const float*)d_in[4];
    const float* W2    = (const float*)d_in[5];
    const float* b2    = (const float*)d_in[6];
    const float* eps   = (const float*)d_in[7];
    const float* gamma = (const float*)d_in[8];
    const float* beta  = (const float*)d_in[9];
    float* out = (float*)d_out;

    // ---- workspace layout ----
    unsigned short* Hb0 = (unsigned short*)d_ws;          // [N,128] bf16
    unsigned short* Hb1 = Hb0 + (size_t)N_NODES * D;      // [N,128] bf16
    float* statsSum = (float*)(Hb1 + (size_t)N_NODES * D);// [128]
    float* statsSq  = statsSum + D;                       // [128]
    float* abn      = statsSq + D;                        // [128]
    float* bbn      = abn + D;                            // [128]
    int*   deg      = (int*)(bbn + D);                    // [N]
    int*   row_ptr  = deg + N_NODES;                      // [N+1]
    int*   blockSum = row_ptr + N_NODES + 1;              // [256]
    int*   edge_pos = blockSum + 256;                     // [E]
    int*   csr_src  = edge_pos + N_EDGES;                 // [E]
    short* Wt       = (short*)(csr_src + N_EDGES);        // [8][128][128]

    const int* src = ei;
    const int* dst = ei + N_EDGES;

    const int edgeBlocks  = (N_EDGES + 255) / 256;       // 3125
    const int scanBlocks  = (N_NODES + 255) / 256;       // 196
    const int layerBlocks = (N_NODES + 63) / 64;         // 782

    // ---- prep (W/x convert, deg/stats zero) + CSR build ----
    prep_kernel<<<6959, 256, 0, stream>>>(W1, W2, x, Wt, (ushort4*)Hb0,
                                          deg, statsSum);
    hist_kernel<<<edgeBlocks, 256, 0, stream>>>(dst, deg, edge_pos);
    scan_block_kernel<<<scanBlocks, 256, 0, stream>>>(deg, row_ptr, blockSum);
    scan_fixup_kernel<<<scanBlocks, 256, 0, stream>>>(blockSum, row_ptr, scanBlocks);
    fill_kernel<<<edgeBlocks, 256, 0, stream>>>(src, dst, row_ptr, edge_pos, csr_src);
    hipMemsetAsync(out, 0, (size_t)NUM_GRAPHS * D * sizeof(float), stream);

    unsigned short* Hin  = Hb0;
    unsigned short* Hout = Hb1;
    for (int layer = 0; layer < 4; ++layer) {
        const float* a = (layer == 0) ? nullptr : abn;
        const float* b = (layer == 0) ? nullptr : bbn;
        const bool bn = (layer < 3);
        layer_kernel<<<layerBlocks, 128, 0, stream>>>(
            (const ushort4*)Hin, row_ptr, csr_src,
            Wt + (size_t)layer * 16384, Wt + (size_t)(4 + layer) * 16384,
            b1 + (size_t)layer * D, b2 + (size_t)layer * D,
            a, b, eps + layer, Hout,
            bn ? statsSum : nullptr, bn ? statsSq : nullptr, N_NODES);
        if (bn) bnscale_kernel<<<1, 128, 0, stream>>>(
            statsSum, statsSq, gamma + (size_t)layer * D, beta + (size_t)layer * D,
            abn, bbn);
        unsigned short* tmp = Hin; Hin = Hout; Hout = tmp;
    }

    // after 4 swaps the final features are back in Hb0 (= Hin)
    pool_kernel<<<scanBlocks, 256, 0, stream>>>(
        (const ushort4*)Hin, batch, out);
}

// Round 9
// 445.140 us; speedup vs baseline: 1.6989x; 1.6989x over previous
//
#include <hip/hip_runtime.h>

#define N_NODES 50000
#define N_EDGES 800000
#define D 128
#define NUM_GRAPHS 128

typedef __attribute__((ext_vector_type(8)))  short bfrag8;
typedef __attribute__((ext_vector_type(16))) float f32x16;

__device__ __forceinline__ float4 f4zero() { return make_float4(0.f, 0.f, 0.f, 0.f); }

__device__ __forceinline__ unsigned short f2bf(float f) {
    unsigned u = __float_as_uint(f);
    unsigned r = (u + 0x7fffu + ((u >> 16) & 1u)) >> 16;
    return (unsigned short)r;
}
__device__ __forceinline__ float bf2f(unsigned short b) {
    return __uint_as_float(((unsigned)b) << 16);
}
__device__ __forceinline__ float4 bf2f4(ushort4 u) {
    return make_float4(bf2f(u.x), bf2f(u.y), bf2f(u.z), bf2f(u.w));
}
__device__ __forceinline__ float4 bnrelu(float4 v, float4 a, float4 b) {
    v.x = fmaxf(a.x * v.x + b.x, 0.f);
    v.y = fmaxf(a.y * v.y + b.y, 0.f);
    v.z = fmaxf(a.z * v.z + b.z, 0.f);
    v.w = fmaxf(a.w * v.w + b.w, 0.f);
    return v;
}
__device__ __forceinline__ void acc4(float4& a, float4 u) {
    a.x += u.x; a.y += u.y; a.z += u.z; a.w += u.w;
}

// ===========================================================================
// prep: W->Wt (bf16 transposed), x->bf16, zero deg, zero stats
// grid = 512 + 6250 + 196 + 1 = 6959
// ===========================================================================
__global__ __launch_bounds__(256) void prep_kernel(
    const float* __restrict__ W1, const float* __restrict__ W2,
    const float* __restrict__ x, short* __restrict__ Wt,
    ushort4* __restrict__ Hb, int* __restrict__ deg, float* __restrict__ stats)
{
    int b = blockIdx.x, t = threadIdx.x;
    if (b < 512) {
        int idx = b * 256 + t;                 // 131072 = 8*128*128
        int m = idx >> 14, rem = idx & 16383;
        int k = rem >> 7, n = rem & 127;
        const float* W = (m < 4) ? (W1 + (size_t)m * 16384)
                                 : (W2 + (size_t)(m - 4) * 16384);
        Wt[(size_t)m * 16384 + n * 128 + k] = (short)f2bf(W[k * 128 + n]);
    } else if (b < 6762) {
        int i = (b - 512) * 256 + t;           // N*32 = 1,600,000 exactly
        float4 v = ((const float4*)x)[i];
        Hb[i] = make_ushort4(f2bf(v.x), f2bf(v.y), f2bf(v.z), f2bf(v.w));
    } else if (b < 6958) {
        int i = (b - 6762) * 256 + t;
        if (i < N_NODES) deg[i] = 0;
    } else {
        stats[t] = 0.f;                        // 256 floats: sum||sq
    }
}

// ===========================================================================
// CSR build: hist (+ per-edge insertion pos), block scan, fixup, fill
// ===========================================================================
__global__ __launch_bounds__(256) void hist_kernel(
    const int* __restrict__ dst, int* __restrict__ deg,
    int* __restrict__ edge_pos)
{
    int e = blockIdx.x * 256 + threadIdx.x;
    if (e < N_EDGES) edge_pos[e] = atomicAdd(&deg[dst[e]], 1);
}

__global__ __launch_bounds__(256) void scan_block_kernel(
    const int* __restrict__ deg, int* __restrict__ row_ptr,
    int* __restrict__ blockSum)
{
    __shared__ int wsum[4];
    int t = threadIdx.x, b = blockIdx.x;
    int i = b * 256 + t;
    int v = (i < N_NODES) ? deg[i] : 0;
    int lane = t & 63, wid = t >> 6;
    #pragma unroll
    for (int off = 1; off < 64; off <<= 1) {
        int u = __shfl_up(v, off, 64);
        if (lane >= off) v += u;
    }
    if (lane == 63) wsum[wid] = v;
    __syncthreads();
    int add = 0;
    for (int w = 0; w < wid; ++w) add += wsum[w];
    v += add;
    if (i < N_NODES) row_ptr[i + 1] = v;
    if (t == 255) blockSum[b] = v;
}

__global__ __launch_bounds__(256) void scan_fixup_kernel(
    const int* __restrict__ blockSum, int* __restrict__ row_ptr, int nb)
{
    __shared__ int wsum[4];
    __shared__ int sbuf[256];
    int t = threadIdx.x, b = blockIdx.x;
    int v = (t < nb) ? blockSum[t] : 0;
    int lane = t & 63, wid = t >> 6;
    #pragma unroll
    for (int off = 1; off < 64; off <<= 1) {
        int u = __shfl_up(v, off, 64);
        if (lane >= off) v += u;
    }
    if (lane == 63) wsum[wid] = v;
    __syncthreads();
    int add = 0;
    for (int w = 0; w < wid; ++w) add += wsum[w];
    sbuf[t] = v + add;
    __syncthreads();
    if (b == 0 && t == 0) row_ptr[0] = 0;
    if (b > 0) {
        int off = sbuf[b - 1];
        int i = b * 256 + t;
        if (i < N_NODES) row_ptr[i + 1] += off;
    }
}

__global__ __launch_bounds__(256) void fill_kernel(
    const int* __restrict__ src, const int* __restrict__ dst,
    const int* __restrict__ row_ptr, const int* __restrict__ edge_pos,
    int* __restrict__ csr_src)
{
    int e = blockIdx.x * 256 + threadIdx.x;
    if (e >= N_EDGES) return;
    csr_src[row_ptr[dst[e]] + edge_pos[e]] = src[e];
}

// ===========================================================================
// Fused gather (bf16 in/out), R6-proven version:
//   A[n] = bf16( (1+eps)*y(h[n]) + sum_{j in N(n)} y(h[j]) )
// y(v) = relu(a*v + b) if BN params given (prev layer's BN), else v.
// 32 lanes per node, ushort4/lane, 8-deep unroll, fp32 accumulation.
// ===========================================================================
__global__ __launch_bounds__(256) void gather_kernel(
    const ushort4* __restrict__ H, const int* __restrict__ row_ptr,
    const int* __restrict__ csr_src, const float* __restrict__ abn,
    const float* __restrict__ bbn, const float* __restrict__ epsp,
    ushort4* __restrict__ A)
{
    int node = blockIdx.x * 8 + (threadIdx.x >> 5);
    if (node >= N_NODES) return;
    int lane = threadIdx.x & 31;
    const bool bn = (abn != nullptr);
    float4 sa = make_float4(1.f, 1.f, 1.f, 1.f);
    float4 sb = f4zero();
    if (bn) { sa = ((const float4*)abn)[lane]; sb = ((const float4*)bbn)[lane]; }
    float eps1 = 1.0f + *epsp;
    int beg = row_ptr[node], end = row_ptr[node + 1];

    float4 v = bf2f4(H[node * 32 + lane]);
    if (bn) v = bnrelu(v, sa, sb);
    float4 acc = make_float4(eps1 * v.x, eps1 * v.y, eps1 * v.z, eps1 * v.w);

    for (int base = beg; base < end; base += 32) {
        int idx = (base + lane < end) ? csr_src[base + lane] : 0;
        int cnt = min(32, end - base);
        int j = 0;
        for (; j + 8 <= cnt; j += 8) {
            int s0 = __shfl(idx, j + 0, 32), s1 = __shfl(idx, j + 1, 32);
            int s2 = __shfl(idx, j + 2, 32), s3 = __shfl(idx, j + 3, 32);
            int s4 = __shfl(idx, j + 4, 32), s5 = __shfl(idx, j + 5, 32);
            int s6 = __shfl(idx, j + 6, 32), s7 = __shfl(idx, j + 7, 32);
            float4 u0 = bf2f4(H[s0 * 32 + lane]);
            float4 u1 = bf2f4(H[s1 * 32 + lane]);
            float4 u2 = bf2f4(H[s2 * 32 + lane]);
            float4 u3 = bf2f4(H[s3 * 32 + lane]);
            float4 u4 = bf2f4(H[s4 * 32 + lane]);
            float4 u5 = bf2f4(H[s5 * 32 + lane]);
            float4 u6 = bf2f4(H[s6 * 32 + lane]);
            float4 u7 = bf2f4(H[s7 * 32 + lane]);
            if (bn) {
                u0 = bnrelu(u0, sa, sb); u1 = bnrelu(u1, sa, sb);
                u2 = bnrelu(u2, sa, sb); u3 = bnrelu(u3, sa, sb);
                u4 = bnrelu(u4, sa, sb); u5 = bnrelu(u5, sa, sb);
                u6 = bnrelu(u6, sa, sb); u7 = bnrelu(u7, sa, sb);
            }
            acc4(acc, u0); acc4(acc, u1); acc4(acc, u2); acc4(acc, u3);
            acc4(acc, u4); acc4(acc, u5); acc4(acc, u6); acc4(acc, u7);
        }
        for (; j < cnt; ++j) {
            int s = __shfl(idx, j, 32);
            float4 u = bf2f4(H[s * 32 + lane]);
            if (bn) u = bnrelu(u, sa, sb);
            acc4(acc, u);
        }
    }
    A[node * 32 + lane] = make_ushort4(f2bf(acc.x), f2bf(acc.y),
                                       f2bf(acc.z), f2bf(acc.w));
}

// ===========================================================================
// Fused MLP (R6-proven):  z2 = (relu(A @ W1 + b1)) @ W2 + b2, bf16 MFMA
// 32x32x16. Block = 128 thr = 2 waves; wave computes 32 rows x 128 cols.
// W1/W2 staged to LDS (32KB, reused) with XOR-chunk swizzle; z1/z2
// round-trip through a swizzled per-wave LDS tile.
// ===========================================================================
__global__ __launch_bounds__(128, 2) void mlp_fused_kernel(
    const ushort* __restrict__ A,
    const short* __restrict__ Wt1,
    const short* __restrict__ Wt2,
    const float* __restrict__ bias1,
    const float* __restrict__ bias2,
    ushort* __restrict__ Hout,
    float* __restrict__ statsSum,
    float* __restrict__ statsSq,
    int M)
{
    __shared__ __align__(16) short Wlds[128 * 128];   // 32 KB
    __shared__ __align__(16) short zlds[2][32 * 128]; // 2 x 8 KB
    __shared__ float ssum[128];
    __shared__ float ssq[128];

    const int tid  = threadIdx.x;
    const int wv   = tid >> 6;
    const int lane = tid & 63;
    const int half = lane >> 5;
    const int ln   = lane & 31;
    const int row0 = blockIdx.x * 64 + wv * 32;
    const bool doStats = (statsSum != nullptr);
    if (doStats) { ssum[tid] = 0.f; ssq[tid] = 0.f; }

    short* zw = &zlds[wv][0];

    // ---- stage W1 -> Wlds (chunk c of row n at c^(n&15)) ----
    {
        const int4* Wg = (const int4*)Wt1;
        int4* Wl = (int4*)Wlds;
        #pragma unroll
        for (int i = 0; i < 16; ++i) {
            int id = i * 128 + tid;
            int n = id >> 4, c = id & 15;
            Wl[n * 16 + (c ^ (n & 15))] = Wg[id];
        }
    }
    __syncthreads();

    // ---- GEMM1: z1 = relu(A@W1 + b1) -> zlds (swizzled A-layout) ----
    {
        f32x16 acc[4];
        #pragma unroll
        for (int ct = 0; ct < 4; ++ct)
            #pragma unroll
            for (int r = 0; r < 16; ++r) acc[ct][r] = 0.f;

        bfrag8 af[8];
        int rowc = min(row0 + ln, M - 1);
        const ushort* ap = A + (size_t)rowc * 128 + half * 8;
        #pragma unroll
        for (int kk = 0; kk < 8; ++kk)
            af[kk] = *(const bfrag8*)(ap + kk * 16);

        #pragma unroll
        for (int kk = 0; kk < 8; ++kk) {
            #pragma unroll
            for (int ct = 0; ct < 4; ++ct) {
                int n = ct * 32 + ln;
                int c = kk * 2 + half;
                bfrag8 bf = *(const bfrag8*)(Wlds + n * 128 + ((c ^ (n & 15)) << 3));
                acc[ct] = __builtin_amdgcn_mfma_f32_32x32x16_bf16(
                    af[kk], bf, acc[ct], 0, 0, 0);
            }
        }
        #pragma unroll
        for (int ct = 0; ct < 4; ++ct) {
            int col = ct * 32 + ln;
            int cc = col >> 3, co = col & 7;
            float bv = bias1[col];
            #pragma unroll
            for (int r = 0; r < 16; ++r) {
                int rloc = (r & 3) + 8 * (r >> 2) + 4 * half;
                float v = fmaxf(acc[ct][r] + bv, 0.f);
                zw[rloc * 128 + ((cc ^ (rloc & 15)) << 3) + co] = (short)f2bf(v);
            }
        }
    }
    __syncthreads();

    // ---- stage W2 -> Wlds ----
    {
        const int4* Wg = (const int4*)Wt2;
        int4* Wl = (int4*)Wlds;
        #pragma unroll
        for (int i = 0; i < 16; ++i) {
            int id = i * 128 + tid;
            int n = id >> 4, c = id & 15;
            Wl[n * 16 + (c ^ (n & 15))] = Wg[id];
        }
    }
    __syncthreads();

    // ---- GEMM2: z2 = z1 @ W2 + b2 ----
    {
        f32x16 acc[4];
        #pragma unroll
        for (int ct = 0; ct < 4; ++ct)
            #pragma unroll
            for (int r = 0; r < 16; ++r) acc[ct][r] = 0.f;

        bfrag8 af[8];
        #pragma unroll
        for (int kk = 0; kk < 8; ++kk) {
            int c = kk * 2 + half;
            af[kk] = *(const bfrag8*)(zw + ln * 128 + ((c ^ (ln & 15)) << 3));
        }
        #pragma unroll
        for (int kk = 0; kk < 8; ++kk) {
            #pragma unroll
            for (int ct = 0; ct < 4; ++ct) {
                int n = ct * 32 + ln;
                int c = kk * 2 + half;
                bfrag8 bf = *(const bfrag8*)(Wlds + n * 128 + ((c ^ (n & 15)) << 3));
                acc[ct] = __builtin_amdgcn_mfma_f32_32x32x16_bf16(
                    af[kk], bf, acc[ct], 0, 0, 0);
            }
        }
        #pragma unroll
        for (int ct = 0; ct < 4; ++ct) {
            int col = ct * 32 + ln;
            int cc = col >> 3, co = col & 7;
            float bv = bias2[col];
            float s = 0.f, sq = 0.f;
            #pragma unroll
            for (int r = 0; r < 16; ++r) {
                int rloc = (r & 3) + 8 * (r >> 2) + 4 * half;
                float v = acc[ct][r] + bv;
                zw[rloc * 128 + ((cc ^ (rloc & 15)) << 3) + co] = (short)f2bf(v);
                if (row0 + rloc < M) { s += v; sq += v * v; }
            }
            if (doStats) {
                s  += __shfl_xor(s, 32);
                sq += __shfl_xor(sq, 32);
                if (half == 0) {
                    atomicAdd(&ssum[col], s);
                    atomicAdd(&ssq[col], sq);
                }
            }
        }
    }
    __syncthreads();

    // ---- coalesced store: zlds -> Hout ----
    {
        const int4* zl = (const int4*)zw;
        int4* Ho = (int4*)Hout;
        #pragma unroll
        for (int i = 0; i < 8; ++i) {
            int id = i * 64 + lane;
            int r = id >> 4, c = id & 15;
            int grow = row0 + r;
            if (grow < M)
                Ho[(size_t)grow * 16 + c] = zl[r * 16 + (c ^ (r & 15))];
        }
    }
    if (doStats) {
        atomicAdd(&statsSum[tid], ssum[tid]);
        atomicAdd(&statsSq[tid],  ssq[tid]);
    }
}

// ===========================================================================
// BN stats -> per-column scale/bias; re-zero stats for next layer
// ===========================================================================
__global__ void bnscale_kernel(
    float* __restrict__ sum, float* __restrict__ sq,
    const float* __restrict__ gamma, const float* __restrict__ beta,
    float* __restrict__ a, float* __restrict__ b)
{
    int c = threadIdx.x;
    float invN = 1.0f / (float)N_NODES;
    float mu = sum[c] * invN;
    float var = sq[c] * invN - mu * mu;
    float ai = gamma[c] * rsqrtf(var + 1e-5f);
    a[c] = ai;
    b[c] = beta[c] - mu * ai;
    sum[c] = 0.f;
    sq[c] = 0.f;
}

// ===========================================================================
// global_add_pool (R6-proven): batch sorted -> run-length accumulate.
// ===========================================================================
__global__ __launch_bounds__(256) void pool_kernel(
    const ushort4* __restrict__ H, const int* __restrict__ batch,
    float* __restrict__ out)
{
    int c4 = threadIdx.x & 31;
    int nl = threadIdx.x >> 5;
    int node0 = blockIdx.x * 256;
    float4 acc = f4zero();
    int gcur = -1;
    for (int i = nl; i < 256; i += 8) {
        int n = node0 + i;
        if (n >= N_NODES) break;
        int g = batch[n];
        if (g != gcur) {
            if (gcur >= 0) {
                float* o = out + gcur * D + c4 * 4;
                atomicAdd(o + 0, acc.x); atomicAdd(o + 1, acc.y);
                atomicAdd(o + 2, acc.z); atomicAdd(o + 3, acc.w);
            }
            gcur = g;
            acc = f4zero();
        }
        float4 v = bf2f4(H[n * 32 + c4]);
        acc4(acc, v);
    }
    if (gcur >= 0) {
        float* o = out + gcur * D + c4 * 4;
        atomicAdd(o + 0, acc.x); atomicAdd(o + 1, acc.y);
        atomicAdd(o + 2, acc.z); atomicAdd(o + 3, acc.w);
    }
}

extern "C" void kernel_launch(void* const* d_in, const int* in_sizes, int n_in,
                              void* d_out, int out_size, void* d_ws, size_t ws_size,
                              hipStream_t stream)
{
    const float* x     = (const float*)d_in[0];
    const int*   ei    = (const int*)d_in[1];
    const int*   batch = (const int*)d_in[2];
    const float* W1    = (const float*)d_in[3];
    const float* b1    = (const float*)d_in[4];
    const float* W2    = (const float*)d_in[5];
    const float* b2    = (const float*)d_in[6];
    const float* eps   = (const float*)d_in[7];
    const float* gamma = (const float*)d_in[8];
    const float* beta  = (const float*)d_in[9];
    float* out = (float*)d_out;

    // ---- workspace layout ----
    unsigned short* Hb  = (unsigned short*)d_ws;          // [N,128] bf16
    unsigned short* Abf = Hb + (size_t)N_NODES * D;       // [N,128] bf16
    float* stats    = (float*)(Abf + (size_t)N_NODES * D);// [256] sum||sq
    float* abn      = stats + 256;                        // [128]
    float* bbn      = abn + 128;                          // [128]
    int*   deg      = (int*)(bbn + 128);                  // [N]
    int*   row_ptr  = deg + N_NODES;                      // [N+1]
    int*   blockSum = row_ptr + N_NODES + 1;              // [256]
    int*   edge_pos = blockSum + 256;                     // [E]
    int*   csr_src  = edge_pos + N_EDGES;                 // [E]
    short* Wt       = (short*)(csr_src + N_EDGES);        // [8][128][128]

    const int* src = ei;
    const int* dst = ei + N_EDGES;

    const int edgeBlocks   = (N_EDGES + 255) / 256;      // 3125
    const int scanBlocks   = (N_NODES + 255) / 256;      // 196
    const int gatherBlocks = (N_NODES + 7) / 8;          // 6250
    const int gemmBlocks   = (N_NODES + 63) / 64;        // 782

    prep_kernel<<<6959, 256, 0, stream>>>(W1, W2, x, Wt, (ushort4*)Hb,
                                          deg, stats);
    hist_kernel<<<edgeBlocks, 256, 0, stream>>>(dst, deg, edge_pos);
    scan_block_kernel<<<scanBlocks, 256, 0, stream>>>(deg, row_ptr, blockSum);
    scan_fixup_kernel<<<scanBlocks, 256, 0, stream>>>(blockSum, row_ptr, scanBlocks);
    fill_kernel<<<edgeBlocks, 256, 0, stream>>>(src, dst, row_ptr, edge_pos, csr_src);

    for (int layer = 0; layer < 4; ++layer) {
        const float* a = (layer == 0) ? nullptr : abn;
        const float* b = (layer == 0) ? nullptr : bbn;
        const bool bn = (layer < 3);
        gather_kernel<<<gatherBlocks, 256, 0, stream>>>(
            (const ushort4*)Hb, row_ptr, csr_src, a, b, eps + layer,
            (ushort4*)Abf);
        mlp_fused_kernel<<<gemmBlocks, 128, 0, stream>>>(
            Abf, Wt + (size_t)layer * 16384, Wt + (size_t)(4 + layer) * 16384,
            b1 + (size_t)layer * D, b2 + (size_t)layer * D, Hb,
            bn ? stats : nullptr, bn ? stats + 128 : nullptr, N_NODES);
        if (bn) bnscale_kernel<<<1, 128, 0, stream>>>(
            stats, stats + 128, gamma + (size_t)layer * D, beta + (size_t)layer * D,
            abn, bbn);
    }

    hipMemsetAsync(out, 0, (size_t)NUM_GRAPHS * D * sizeof(float), stream);
    pool_kernel<<<scanBlocks, 256, 0, stream>>>(
        (const ushort4*)Hb, batch, out);
}

// Round 10
// 423.355 us; speedup vs baseline: 1.7863x; 1.0515x over previous
//
#include <hip/hip_runtime.h>

#define N_NODES 50000
#define N_EDGES 800000
#define D 128
#define NUM_GRAPHS 128

typedef __attribute__((ext_vector_type(8)))  short bfrag8;
typedef __attribute__((ext_vector_type(16))) float f32x16;

__device__ __forceinline__ float4 f4zero() { return make_float4(0.f, 0.f, 0.f, 0.f); }

__device__ __forceinline__ unsigned short f2bf(float f) {
    unsigned u = __float_as_uint(f);
    unsigned r = (u + 0x7fffu + ((u >> 16) & 1u)) >> 16;
    return (unsigned short)r;
}
__device__ __forceinline__ float bf2f(unsigned short b) {
    return __uint_as_float(((unsigned)b) << 16);
}
__device__ __forceinline__ float4 bf2f4(ushort4 u) {
    return make_float4(bf2f(u.x), bf2f(u.y), bf2f(u.z), bf2f(u.w));
}
__device__ __forceinline__ float4 bnrelu(float4 v, float4 a, float4 b) {
    v.x = fmaxf(a.x * v.x + b.x, 0.f);
    v.y = fmaxf(a.y * v.y + b.y, 0.f);
    v.z = fmaxf(a.z * v.z + b.z, 0.f);
    v.w = fmaxf(a.w * v.w + b.w, 0.f);
    return v;
}
__device__ __forceinline__ void acc4(float4& a, float4 u) {
    a.x += u.x; a.y += u.y; a.z += u.z; a.w += u.w;
}

// ===========================================================================
// prep: W->Wt (bf16 transposed), x->bf16, zero deg, zero stats (3 layers)
// grid = 512 + 6250 + 196 + 3 = 6961
// ===========================================================================
__global__ __launch_bounds__(256) void prep_kernel(
    const float* __restrict__ W1, const float* __restrict__ W2,
    const float* __restrict__ x, short* __restrict__ Wt,
    ushort4* __restrict__ Hb, int* __restrict__ deg, float* __restrict__ stats)
{
    int b = blockIdx.x, t = threadIdx.x;
    if (b < 512) {
        int idx = b * 256 + t;                 // 131072 = 8*128*128
        int m = idx >> 14, rem = idx & 16383;
        int k = rem >> 7, n = rem & 127;
        const float* W = (m < 4) ? (W1 + (size_t)m * 16384)
                                 : (W2 + (size_t)(m - 4) * 16384);
        Wt[(size_t)m * 16384 + n * 128 + k] = (short)f2bf(W[k * 128 + n]);
    } else if (b < 6762) {
        int i = (b - 512) * 256 + t;           // N*32 = 1,600,000 exactly
        float4 v = ((const float4*)x)[i];
        Hb[i] = make_ushort4(f2bf(v.x), f2bf(v.y), f2bf(v.z), f2bf(v.w));
    } else if (b < 6958) {
        int i = (b - 6762) * 256 + t;
        if (i < N_NODES) deg[i] = 0;
    } else {
        int i = (b - 6958) * 256 + t;          // 768 floats: 3 x (sum||sq)
        stats[i] = 0.f;
    }
}

// ===========================================================================
// CSR build: hist (+ per-edge insertion pos), block scan, fixup, fill
// ===========================================================================
__global__ __launch_bounds__(256) void hist_kernel(
    const int* __restrict__ dst, int* __restrict__ deg,
    int* __restrict__ edge_pos)
{
    int e = blockIdx.x * 256 + threadIdx.x;
    if (e < N_EDGES) edge_pos[e] = atomicAdd(&deg[dst[e]], 1);
}

__global__ __launch_bounds__(256) void scan_block_kernel(
    const int* __restrict__ deg, int* __restrict__ row_ptr,
    int* __restrict__ blockSum)
{
    __shared__ int wsum[4];
    int t = threadIdx.x, b = blockIdx.x;
    int i = b * 256 + t;
    int v = (i < N_NODES) ? deg[i] : 0;
    int lane = t & 63, wid = t >> 6;
    #pragma unroll
    for (int off = 1; off < 64; off <<= 1) {
        int u = __shfl_up(v, off, 64);
        if (lane >= off) v += u;
    }
    if (lane == 63) wsum[wid] = v;
    __syncthreads();
    int add = 0;
    for (int w = 0; w < wid; ++w) add += wsum[w];
    v += add;
    if (i < N_NODES) row_ptr[i + 1] = v;
    if (t == 255) blockSum[b] = v;
}

__global__ __launch_bounds__(256) void scan_fixup_kernel(
    const int* __restrict__ blockSum, int* __restrict__ row_ptr, int nb)
{
    __shared__ int wsum[4];
    __shared__ int sbuf[256];
    int t = threadIdx.x, b = blockIdx.x;
    int v = (t < nb) ? blockSum[t] : 0;
    int lane = t & 63, wid = t >> 6;
    #pragma unroll
    for (int off = 1; off < 64; off <<= 1) {
        int u = __shfl_up(v, off, 64);
        if (lane >= off) v += u;
    }
    if (lane == 63) wsum[wid] = v;
    __syncthreads();
    int add = 0;
    for (int w = 0; w < wid; ++w) add += wsum[w];
    sbuf[t] = v + add;
    __syncthreads();
    if (b == 0 && t == 0) row_ptr[0] = 0;
    if (b > 0) {
        int off = sbuf[b - 1];
        int i = b * 256 + t;
        if (i < N_NODES) row_ptr[i + 1] += off;
    }
}

__global__ __launch_bounds__(256) void fill_kernel(
    const int* __restrict__ src, const int* __restrict__ dst,
    const int* __restrict__ row_ptr, const int* __restrict__ edge_pos,
    int* __restrict__ csr_src)
{
    int e = blockIdx.x * 256 + threadIdx.x;
    if (e >= N_EDGES) return;
    csr_src[row_ptr[dst[e]] + edge_pos[e]] = src[e];
}

// ===========================================================================
// Fused gather (R6-proven body) + in-kernel BN-scale derivation:
//   A[n] = bf16( (1+eps)*y(h[n]) + sum_{j in N(n)} y(h[j]) )
// y(v) = relu(a*v + b) with a,b computed from prev layer's raw stats.
// 32 lanes per node, ushort4/lane, 8-deep unroll, fp32 accumulation.
// ===========================================================================
__global__ __launch_bounds__(256) void gather_kernel(
    const ushort4* __restrict__ H, const int* __restrict__ row_ptr,
    const int* __restrict__ csr_src,
    const float* __restrict__ stats,      // [256] sum||sq of prev layer, or null
    const float* __restrict__ gamma, const float* __restrict__ beta,
    const float* __restrict__ epsp,
    ushort4* __restrict__ A)
{
    int node = blockIdx.x * 8 + (threadIdx.x >> 5);
    if (node >= N_NODES) return;
    int lane = threadIdx.x & 31;
    const bool bn = (stats != nullptr);
    float4 sa = make_float4(1.f, 1.f, 1.f, 1.f);
    float4 sb = f4zero();
    if (bn) {
        const float invN = 1.0f / (float)N_NODES;
        float m0 = stats[lane * 4 + 0] * invN, m1 = stats[lane * 4 + 1] * invN;
        float m2 = stats[lane * 4 + 2] * invN, m3 = stats[lane * 4 + 3] * invN;
        sa.x = gamma[lane * 4 + 0] * rsqrtf(stats[128 + lane * 4 + 0] * invN - m0 * m0 + 1e-5f);
        sa.y = gamma[lane * 4 + 1] * rsqrtf(stats[128 + lane * 4 + 1] * invN - m1 * m1 + 1e-5f);
        sa.z = gamma[lane * 4 + 2] * rsqrtf(stats[128 + lane * 4 + 2] * invN - m2 * m2 + 1e-5f);
        sa.w = gamma[lane * 4 + 3] * rsqrtf(stats[128 + lane * 4 + 3] * invN - m3 * m3 + 1e-5f);
        sb.x = beta[lane * 4 + 0] - m0 * sa.x;
        sb.y = beta[lane * 4 + 1] - m1 * sa.y;
        sb.z = beta[lane * 4 + 2] - m2 * sa.z;
        sb.w = beta[lane * 4 + 3] - m3 * sa.w;
    }
    float eps1 = 1.0f + *epsp;
    int beg = row_ptr[node], end = row_ptr[node + 1];

    float4 v = bf2f4(H[node * 32 + lane]);
    if (bn) v = bnrelu(v, sa, sb);
    float4 acc = make_float4(eps1 * v.x, eps1 * v.y, eps1 * v.z, eps1 * v.w);

    for (int base = beg; base < end; base += 32) {
        int idx = (base + lane < end) ? csr_src[base + lane] : 0;
        int cnt = min(32, end - base);
        int j = 0;
        for (; j + 8 <= cnt; j += 8) {
            int s0 = __shfl(idx, j + 0, 32), s1 = __shfl(idx, j + 1, 32);
            int s2 = __shfl(idx, j + 2, 32), s3 = __shfl(idx, j + 3, 32);
            int s4 = __shfl(idx, j + 4, 32), s5 = __shfl(idx, j + 5, 32);
            int s6 = __shfl(idx, j + 6, 32), s7 = __shfl(idx, j + 7, 32);
            float4 u0 = bf2f4(H[s0 * 32 + lane]);
            float4 u1 = bf2f4(H[s1 * 32 + lane]);
            float4 u2 = bf2f4(H[s2 * 32 + lane]);
            float4 u3 = bf2f4(H[s3 * 32 + lane]);
            float4 u4 = bf2f4(H[s4 * 32 + lane]);
            float4 u5 = bf2f4(H[s5 * 32 + lane]);
            float4 u6 = bf2f4(H[s6 * 32 + lane]);
            float4 u7 = bf2f4(H[s7 * 32 + lane]);
            if (bn) {
                u0 = bnrelu(u0, sa, sb); u1 = bnrelu(u1, sa, sb);
                u2 = bnrelu(u2, sa, sb); u3 = bnrelu(u3, sa, sb);
                u4 = bnrelu(u4, sa, sb); u5 = bnrelu(u5, sa, sb);
                u6 = bnrelu(u6, sa, sb); u7 = bnrelu(u7, sa, sb);
            }
            acc4(acc, u0); acc4(acc, u1); acc4(acc, u2); acc4(acc, u3);
            acc4(acc, u4); acc4(acc, u5); acc4(acc, u6); acc4(acc, u7);
        }
        for (; j < cnt; ++j) {
            int s = __shfl(idx, j, 32);
            float4 u = bf2f4(H[s * 32 + lane]);
            if (bn) u = bnrelu(u, sa, sb);
            acc4(acc, u);
        }
    }
    A[node * 32 + lane] = make_ushort4(f2bf(acc.x), f2bf(acc.y),
                                       f2bf(acc.z), f2bf(acc.w));
}

// ===========================================================================
// Fused MLP:  z2 = (relu(A @ W1 + b1)) @ W2 + b2, bf16 MFMA 32x32x16.
// Block = 256 thr = 4 waves over a 64-row tile: wave wv -> row-group
// rg=wv&1 (rows rg*32..+32), col-half ch=wv>>1 (cols ch*64..+64).
// W1/W2 staged to LDS (32KB, reused) with XOR-chunk swizzle; z1/z2
// round-trip through zlds[rg] (32x128 bf16, shared by the 2 ch-waves).
// Same swizzle formulas as the R6-proven 128-thr version.
// ===========================================================================
__global__ __launch_bounds__(256, 3) void mlp_fused_kernel(
    const ushort* __restrict__ A,
    const short* __restrict__ Wt1,
    const short* __restrict__ Wt2,
    const float* __restrict__ bias1,
    const float* __restrict__ bias2,
    ushort* __restrict__ Hout,
    float* __restrict__ statsSum,
    float* __restrict__ statsSq,
    int M)
{
    __shared__ __align__(16) short Wlds[128 * 128];   // 32 KB
    __shared__ __align__(16) short zlds[2][32 * 128]; // 16 KB
    __shared__ float ssum[128];
    __shared__ float ssq[128];

    const int tid  = threadIdx.x;
    const int wv   = tid >> 6;
    const int lane = tid & 63;
    const int half = lane >> 5;
    const int ln   = lane & 31;
    const int rg   = wv & 1;
    const int ch   = wv >> 1;
    const int row0 = blockIdx.x * 64 + rg * 32;
    const bool doStats = (statsSum != nullptr);
    if (doStats && tid < 128) { ssum[tid] = 0.f; ssq[tid] = 0.f; }

    short* zw = &zlds[rg][0];

    // ---- stage W1 -> Wlds (chunk c of row n at c^(n&15)) ----
    {
        const int4* Wg = (const int4*)Wt1;
        int4* Wl = (int4*)Wlds;
        #pragma unroll
        for (int i = 0; i < 8; ++i) {
            int id = i * 256 + tid;            // 2048 int4
            int n = id >> 4, c = id & 15;
            Wl[n * 16 + (c ^ (n & 15))] = Wg[id];
        }
    }
    __syncthreads();   // S0: W1 staged, ssum init

    // ---- GEMM1: z1 = relu(A@W1 + b1) -> zlds[rg] ----
    {
        f32x16 acc[2];
        #pragma unroll
        for (int ci = 0; ci < 2; ++ci)
            #pragma unroll
            for (int r = 0; r < 16; ++r) acc[ci][r] = 0.f;

        bfrag8 af[8];
        int rowc = min(row0 + ln, M - 1);
        const ushort* ap = A + (size_t)rowc * 128 + half * 8;
        #pragma unroll
        for (int kk = 0; kk < 8; ++kk)
            af[kk] = *(const bfrag8*)(ap + kk * 16);

        #pragma unroll
        for (int kk = 0; kk < 8; ++kk) {
            #pragma unroll
            for (int ci = 0; ci < 2; ++ci) {
                int n = (ch * 2 + ci) * 32 + ln;
                int c = kk * 2 + half;
                bfrag8 bf = *(const bfrag8*)(Wlds + n * 128 + ((c ^ (n & 15)) << 3));
                acc[ci] = __builtin_amdgcn_mfma_f32_32x32x16_bf16(
                    af[kk], bf, acc[ci], 0, 0, 0);
            }
        }
        #pragma unroll
        for (int ci = 0; ci < 2; ++ci) {
            int col = (ch * 2 + ci) * 32 + ln;
            int cc = col >> 3, co = col & 7;
            float bv = bias1[col];
            #pragma unroll
            for (int r = 0; r < 16; ++r) {
                int rloc = (r & 3) + 8 * (r >> 2) + 4 * half;
                float v = fmaxf(acc[ci][r] + bv, 0.f);
                zw[rloc * 128 + ((cc ^ (rloc & 15)) << 3) + co] = (short)f2bf(v);
            }
        }
    }
    __syncthreads();   // S1: z1 complete, G1 Wlds reads done

    // ---- stage W2 -> Wlds; preload af2 from zlds[rg] ----
    bfrag8 af2[8];
    #pragma unroll
    for (int kk = 0; kk < 8; ++kk) {
        int c = kk * 2 + half;
        af2[kk] = *(const bfrag8*)(zw + ln * 128 + ((c ^ (ln & 15)) << 3));
    }
    {
        const int4* Wg = (const int4*)Wt2;
        int4* Wl = (int4*)Wlds;
        #pragma unroll
        for (int i = 0; i < 8; ++i) {
            int id = i * 256 + tid;
            int n = id >> 4, c = id & 15;
            Wl[n * 16 + (c ^ (n & 15))] = Wg[id];
        }
    }
    __syncthreads();   // S2: W2 staged, all af2 preloads done

    // ---- GEMM2: z2 = z1 @ W2 + b2 -> zlds[rg]; stats on fp32 values ----
    {
        f32x16 acc[2];
        #pragma unroll
        for (int ci = 0; ci < 2; ++ci)
            #pragma unroll
            for (int r = 0; r < 16; ++r) acc[ci][r] = 0.f;

        #pragma unroll
        for (int kk = 0; kk < 8; ++kk) {
            #pragma unroll
            for (int ci = 0; ci < 2; ++ci) {
                int n = (ch * 2 + ci) * 32 + ln;
                int c = kk * 2 + half;
                bfrag8 bf = *(const bfrag8*)(Wlds + n * 128 + ((c ^ (n & 15)) << 3));
                acc[ci] = __builtin_amdgcn_mfma_f32_32x32x16_bf16(
                    af2[kk], bf, acc[ci], 0, 0, 0);
            }
        }
        #pragma unroll
        for (int ci = 0; ci < 2; ++ci) {
            int col = (ch * 2 + ci) * 32 + ln;
            int cc = col >> 3, co = col & 7;
            float bv = bias2[col];
            float s = 0.f, sq = 0.f;
            #pragma unroll
            for (int r = 0; r < 16; ++r) {
                int rloc = (r & 3) + 8 * (r >> 2) + 4 * half;
                float v = acc[ci][r] + bv;
                zw[rloc * 128 + ((cc ^ (rloc & 15)) << 3) + co] = (short)f2bf(v);
                if (row0 + rloc < M) { s += v; sq += v * v; }
            }
            if (doStats) {
                s  += __shfl_xor(s, 32);
                sq += __shfl_xor(sq, 32);
                if (half == 0) {
                    atomicAdd(&ssum[col], s);
                    atomicAdd(&ssq[col], sq);
                }
            }
        }
    }
    __syncthreads();   // S3: z2 complete, ssum atomics done

    // ---- coalesced store: zlds -> Hout (64 rows x 16 int4) ----
    {
        int4* Ho = (int4*)Hout;
        #pragma unroll
        for (int i = 0; i < 4; ++i) {
            int id = i * 256 + tid;            // 1024 int4
            int r = id >> 4, c = id & 15;
            int rl = r & 31;
            int grow = blockIdx.x * 64 + r;
            if (grow < M)
                Ho[(size_t)grow * 16 + c] =
                    ((const int4*)&zlds[r >> 5][0])[rl * 16 + (c ^ (rl & 15))];
        }
    }
    if (doStats && tid < 128) {
        atomicAdd(&statsSum[tid], ssum[tid]);
        atomicAdd(&statsSq[tid],  ssq[tid]);
    }
}

// ===========================================================================
// global_add_pool (R6-proven): batch sorted -> run-length accumulate.
// ===========================================================================
__global__ __launch_bounds__(256) void pool_kernel(
    const ushort4* __restrict__ H, const int* __restrict__ batch,
    float* __restrict__ out)
{
    int c4 = threadIdx.x & 31;
    int nl = threadIdx.x >> 5;
    int node0 = blockIdx.x * 256;
    float4 acc = f4zero();
    int gcur = -1;
    for (int i = nl; i < 256; i += 8) {
        int n = node0 + i;
        if (n >= N_NODES) break;
        int g = batch[n];
        if (g != gcur) {
            if (gcur >= 0) {
                float* o = out + gcur * D + c4 * 4;
                atomicAdd(o + 0, acc.x); atomicAdd(o + 1, acc.y);
                atomicAdd(o + 2, acc.z); atomicAdd(o + 3, acc.w);
            }
            gcur = g;
            acc = f4zero();
        }
        float4 v = bf2f4(H[n * 32 + c4]);
        acc4(acc, v);
    }
    if (gcur >= 0) {
        float* o = out + gcur * D + c4 * 4;
        atomicAdd(o + 0, acc.x); atomicAdd(o + 1, acc.y);
        atomicAdd(o + 2, acc.z); atomicAdd(o + 3, acc.w);
    }
}

extern "C" void kernel_launch(void* const* d_in, const int* in_sizes, int n_in,
                              void* d_out, int out_size, void* d_ws, size_t ws_size,
                              hipStream_t stream)
{
    const float* x     = (const float*)d_in[0];
    const int*   ei    = (const int*)d_in[1];
    const int*   batch = (const int*)d_in[2];
    const float* W1    = (const float*)d_in[3];
    const float* b1    = (const float*)d_in[4];
    const float* W2    = (const float*)d_in[5];
    const float* b2    = (const float*)d_in[6];
    const float* eps   = (const float*)d_in[7];
    const float* gamma = (const float*)d_in[8];
    const float* beta  = (const float*)d_in[9];
    float* out = (float*)d_out;

    // ---- workspace layout ----
    unsigned short* Hb  = (unsigned short*)d_ws;          // [N,128] bf16
    unsigned short* Abf = Hb + (size_t)N_NODES * D;       // [N,128] bf16
    float* stats    = (float*)(Abf + (size_t)N_NODES * D);// [3][256] sum||sq
    int*   deg      = (int*)(stats + 3 * 256);            // [N]
    int*   row_ptr  = deg + N_NODES;                      // [N+1]
    int*   blockSum = row_ptr + N_NODES + 1;              // [256]
    int*   edge_pos = blockSum + 256;                     // [E]
    int*   csr_src  = edge_pos + N_EDGES;                 // [E]
    short* Wt       = (short*)(csr_src + N_EDGES);        // [8][128][128]

    const int* src = ei;
    const int* dst = ei + N_EDGES;

    const int edgeBlocks   = (N_EDGES + 255) / 256;      // 3125
    const int scanBlocks   = (N_NODES + 255) / 256;      // 196
    const int gatherBlocks = (N_NODES + 7) / 8;          // 6250
    const int gemmBlocks   = (N_NODES + 63) / 64;        // 782

    prep_kernel<<<6961, 256, 0, stream>>>(W1, W2, x, Wt, (ushort4*)Hb,
                                          deg, stats);
    hist_kernel<<<edgeBlocks, 256, 0, stream>>>(dst, deg, edge_pos);
    scan_block_kernel<<<scanBlocks, 256, 0, stream>>>(deg, row_ptr, blockSum);
    scan_fixup_kernel<<<scanBlocks, 256, 0, stream>>>(blockSum, row_ptr, scanBlocks);
    fill_kernel<<<edgeBlocks, 256, 0, stream>>>(src, dst, row_ptr, edge_pos, csr_src);

    for (int layer = 0; layer < 4; ++layer) {
        const bool bn = (layer < 3);
        const float* statPrev = (layer == 0) ? nullptr : stats + (layer - 1) * 256;
        int gl = (layer > 0) ? layer - 1 : 0;
        gather_kernel<<<gatherBlocks, 256, 0, stream>>>(
            (const ushort4*)Hb, row_ptr, csr_src, statPrev,
            gamma + (size_t)gl * D, beta + (size_t)gl * D,
            eps + layer, (ushort4*)Abf);
        mlp_fused_kernel<<<gemmBlocks, 256, 0, stream>>>(
            Abf, Wt + (size_t)layer * 16384, Wt + (size_t)(4 + layer) * 16384,
            b1 + (size_t)layer * D, b2 + (size_t)layer * D, Hb,
            bn ? stats + layer * 256 : nullptr,
            bn ? stats + layer * 256 + 128 : nullptr, N_NODES);
    }

    hipMemsetAsync(out, 0, (size_t)NUM_GRAPHS * D * sizeof(float), stream);
    pool_kernel<<<scanBlocks, 256, 0, stream>>>(
        (const ushort4*)Hb, batch, out);
}